// Round 9
// baseline (90.951 us; speedup 1.0000x reference)
//
#include <hip/hip_runtime.h>
#include <hip/hip_bf16.h>

#define H_ 256
#define W_ 256
#define C_ 128
#define NBPOS 1024   // N * 16 * 16 block positions
#define NACT 512

typedef __bf16 bf16x8 __attribute__((ext_vector_type(8)));
typedef float f32x4 __attribute__((ext_vector_type(4)));

// workspace layout (bytes)
#define SCALE_OFF 294912
#define SHIFT_OFF 295424
#define INACT_OFF 295936

// Blocks 0..575: weight repack fp32 HWIO -> bf16 [tap][cin8][cout][8].
// Block 576: BN fold + inactive-block list (bitmap + compaction).
__global__ void prep_kernel(const float* __restrict__ w, const float* __restrict__ b,
                            const float* __restrict__ gamma, const float* __restrict__ beta,
                            const float* __restrict__ mean, const float* __restrict__ var,
                            const int* __restrict__ active,
                            __bf16* __restrict__ wprep, float* __restrict__ scale,
                            float* __restrict__ shift, int* __restrict__ inact) {
  int blk = blockIdx.x, tid = threadIdx.x;
  if (blk < 576) {
    int o = blk * 256 + tid;
    int j = o & 7, cout = (o >> 3) & 127, k8 = (o >> 10) & 15, tap = o >> 14;
    wprep[o] = (__bf16)w[((size_t)tap * 128 + k8 * 8 + j) * 128 + cout];
    return;
  }
  __shared__ unsigned mask[32];
  __shared__ int cnt;
  if (tid < 32) mask[tid] = 0u;
  if (tid == 0) cnt = 0;
  __syncthreads();
  for (int i = tid; i < NACT; i += 256) {
    int a = active[i];
    atomicOr(&mask[a >> 5], 1u << (a & 31));
  }
  if (tid < 128) {
    float s = gamma[tid] * rsqrtf(var[tid] + 1e-3f);
    scale[tid] = s;
    shift[tid] = (b[tid] - mean[tid]) * s + beta[tid];
  }
  __syncthreads();
  for (int p = tid; p < NBPOS; p += 256) {
    if (!((mask[p >> 5] >> (p & 31)) & 1u)) {
      int q = atomicAdd(&cnt, 1);
      inact[q] = p;   // order nondeterministic; disjoint coverage is what matters
    }
  }
}

// ONE main kernel, 1024 wgs: even idx -> conv of active[idx>>1] (full 16x16
// block, M=256 implicit GEMM), odd idx -> stream-copy of inact[idx>>1].
// Conv register tile per wave: 4 M-frags x 8 N-frags -> 0.375 LDS frag-reads
// per MFMA (vs 0.625 for the M-split variant) — the kernel is LDS-BW-bound,
// so this is the first-order lever. A: 18x18px x 64ch bf16 LDS, XOR-swizzled,
// two channel halves. B: ldsB ping-pong, write-one-ahead, ONE barrier/K-step.
__global__ __launch_bounds__(256, 2) void main_kernel(
    const float* __restrict__ x, const __bf16* __restrict__ wprep,
    const float* __restrict__ scale, const float* __restrict__ shift,
    const int* __restrict__ active, const int* __restrict__ inact,
    float* __restrict__ y) {
  __shared__ unsigned char ldsA[324 * 128];   // 18*18 px x 64ch bf16 = 41472 B
  __shared__ unsigned char ldsB[2][8192];     // ping-pong 32k x 128cout bf16

  const int idx = blockIdx.x;
  const int tid = threadIdx.x;

  if (idx & 1) {
    // ---- copy path: inactive block, no barriers, NT stores ----
    const int cid = inact[idx >> 1];
    const int cn = cid >> 8, cy = (cid >> 4) & 15, cx = cid & 15;
    const size_t base4 = ((((size_t)cn * H_ + cy * 16) * W_ + cx * 16) * C_) >> 2;
    const f32x4* __restrict__ xs = (const f32x4*)x;
    f32x4* __restrict__ ys = (f32x4*)y;
#pragma unroll 4
    for (int i = 0; i < 32; ++i) {
      int lin = (i << 8) + tid;
      int row = lin >> 9, rem = lin & 511;
      size_t idx4 = base4 + (size_t)row * (W_ * C_ / 4) + rem;
      f32x4 v = xs[idx4];
      __builtin_nontemporal_store(v, &ys[idx4]);
    }
    return;
  }

  // ---- conv path ----
  const int lane = tid & 63;
  const int wid = tid >> 6;
  const int aid = active[idx >> 1];
  const int bn = aid >> 8, by = (aid >> 4) & 15, bx = aid & 15;
  const int h0 = by * 16, w0 = bx * 16;
  const float* xb = x + (size_t)bn * (H_ * W_ * C_);

  f32x4 acc[4][8];
  f32x4 zero = {0.f, 0.f, 0.f, 0.f};
#pragma unroll
  for (int i = 0; i < 4; ++i)
#pragma unroll
    for (int jj = 0; jj < 8; ++jj) acc[i][jj] = zero;

  const uint4* wp4 = (const uint4*)wprep;
  uint4 t0, t1;
  auto load_t = [&](int u) {                  // weight tile for flat K-step u
    int ks = u % 18, h = u / 18;
    int tile = ((ks >> 1) << 2) + (h << 1) + (ks & 1);
    t0 = wp4[tile * 512 + tid];
    t1 = wp4[tile * 512 + 256 + tid];
  };
  auto stage = [&](int half) {                // 18x18 px x 64ch -> bf16 LDS, XOR-swizzled
    for (int u = tid; u < 324 * 8; u += 256) {
      int s = u >> 3, c8 = u & 7;
      int iy = s / 18, ix = s - iy * 18;
      int hs = h0 + iy, wsp = w0 + ix;
      float4 f0 = make_float4(0.f, 0.f, 0.f, 0.f), f1 = f0;
      if (hs < H_ && wsp < W_) {
        const float* p = xb + (size_t)(hs * W_ + wsp) * C_ + half * 64 + c8 * 8;
        f0 = *(const float4*)p;
        f1 = *(const float4*)(p + 4);
      }
      bf16x8 v;
      v[0] = (__bf16)f0.x; v[1] = (__bf16)f0.y; v[2] = (__bf16)f0.z; v[3] = (__bf16)f0.w;
      v[4] = (__bf16)f1.x; v[5] = (__bf16)f1.y; v[6] = (__bf16)f1.z; v[7] = (__bf16)f1.w;
      int lin = s * 128 + c8 * 16;
      *(bf16x8*)(&ldsA[lin ^ ((s & 7) << 4)]) = v;
    }
  };

  // prologue
  load_t(0);
  stage(0);
  ((uint4*)ldsB[0])[tid] = t0;
  ((uint4*)ldsB[0])[256 + tid] = t1;
  load_t(1);
  __syncthreads();

  const int koff = (lane >> 4) * 16;          // 16B k-chunk within 32 channels
  const int colb = (lane & 15) * 16;
  const int krow = (lane >> 4) * 2048;

  for (int u = 0; u < 36; ++u) {
    int cur = u & 1;
    if (u < 35) {
      ((uint4*)ldsB[cur ^ 1])[tid] = t0;      // tile u+1
      ((uint4*)ldsB[cur ^ 1])[256 + tid] = t1;
      if (u < 34) load_t(u + 2);
    }
    int ks = u % 18;
    int tap = ks >> 1, kch = ks & 1;
    int dyv = tap / 3, dxv = tap - dyv * 3;

    bf16x8 a[4];
#pragma unroll
    for (int mi = 0; mi < 4; ++mi) {
      int srow = (wid * 4 + mi + dyv) * 18 + dxv + (lane & 15);
      int lin = srow * 128 + kch * 64 + koff;
      a[mi] = *(const bf16x8*)(&ldsA[lin ^ ((srow & 7) << 4)]);
    }
    bf16x8 bfr[8];
#pragma unroll
    for (int nb = 0; nb < 8; ++nb)
      bfr[nb] = *(const bf16x8*)(&ldsB[cur][krow + nb * 256 + colb]);
#pragma unroll
    for (int mi = 0; mi < 4; ++mi)
#pragma unroll
      for (int nb = 0; nb < 8; ++nb)
        acc[mi][nb] = __builtin_amdgcn_mfma_f32_16x16x32_bf16(a[mi], bfr[nb], acc[mi][nb], 0, 0, 0);

    __syncthreads();                          // ldsB[cur] reads done; u+1 writes visible
    if (u == 17) {                            // re-stage ldsA with channel half 1
      stage(1);
      __syncthreads();
    }
  }

  // epilogue: BN + ReLU + scatter. D frag: col=lane&15, row=(lane>>4)*4+reg
  const int colc = lane & 15;
  float sc[8], sh[8];
#pragma unroll
  for (int nb = 0; nb < 8; ++nb) {
    sc[nb] = scale[nb * 16 + colc];
    sh[nb] = shift[nb * 16 + colc];
  }
  float* yb = y + (((size_t)bn * H_ + h0) * W_ + w0) * C_;
#pragma unroll
  for (int mi = 0; mi < 4; ++mi) {
    int oy = wid * 4 + mi;
#pragma unroll
    for (int r = 0; r < 4; ++r) {
      int ox = (lane >> 4) * 4 + r;
      float* yr = yb + ((size_t)oy * W_ + ox) * C_;
#pragma unroll
      for (int nb = 0; nb < 8; ++nb) {
        float v = acc[mi][nb][r] * sc[nb] + sh[nb];
        __builtin_nontemporal_store(fmaxf(v, 0.f), &yr[nb * 16 + colc]);
      }
    }
  }
}

extern "C" void kernel_launch(void* const* d_in, const int* in_sizes, int n_in,
                              void* d_out, int out_size, void* d_ws, size_t ws_size,
                              hipStream_t stream) {
  const float* x     = (const float*)d_in[0];
  const float* w     = (const float*)d_in[1];
  const float* b     = (const float*)d_in[2];
  const float* gamma = (const float*)d_in[3];
  const float* beta  = (const float*)d_in[4];
  const float* mean  = (const float*)d_in[5];
  const float* var   = (const float*)d_in[6];
  const int*   act   = (const int*)d_in[7];
  float* y = (float*)d_out;
  char* ws = (char*)d_ws;
  __bf16* wprep = (__bf16*)ws;
  float* scale = (float*)(ws + SCALE_OFF);
  float* shift = (float*)(ws + SHIFT_OFF);
  int* inact = (int*)(ws + INACT_OFF);

  prep_kernel<<<dim3(577), dim3(256), 0, stream>>>(w, b, gamma, beta, mean, var, act,
                                                   wprep, scale, shift, inact);
  main_kernel<<<dim3(1024), dim3(256), 0, stream>>>(x, wprep, scale, shift, act, inact, y);
}

// Round 10
// 81.409 us; speedup vs baseline: 1.1172x; 1.1172x over previous
//
#include <hip/hip_runtime.h>
#include <hip/hip_bf16.h>

#define H_ 256
#define W_ 256
#define C_ 128
#define NBPOS 1024   // N * 16 * 16 block positions
#define NACT 512

typedef __bf16 bf16x8 __attribute__((ext_vector_type(8)));
typedef float f32x4 __attribute__((ext_vector_type(4)));

// workspace layout (bytes)
#define SCALE_OFF 294912
#define SHIFT_OFF 295424
#define INACT_OFF 295936

// Blocks 0..575: weight repack fp32 HWIO -> bf16 [tap][cin8][cout][8].
// Block 576: BN fold + inactive-block list (bitmap + compaction).
__global__ void prep_kernel(const float* __restrict__ w, const float* __restrict__ b,
                            const float* __restrict__ gamma, const float* __restrict__ beta,
                            const float* __restrict__ mean, const float* __restrict__ var,
                            const int* __restrict__ active,
                            __bf16* __restrict__ wprep, float* __restrict__ scale,
                            float* __restrict__ shift, int* __restrict__ inact) {
  int blk = blockIdx.x, tid = threadIdx.x;
  if (blk < 576) {
    int o = blk * 256 + tid;
    int j = o & 7, cout = (o >> 3) & 127, k8 = (o >> 10) & 15, tap = o >> 14;
    wprep[o] = (__bf16)w[((size_t)tap * 128 + k8 * 8 + j) * 128 + cout];
    return;
  }
  __shared__ unsigned mask[32];
  __shared__ int cnt;
  if (tid < 32) mask[tid] = 0u;
  if (tid == 0) cnt = 0;
  __syncthreads();
  for (int i = tid; i < NACT; i += 256) {
    int a = active[i];
    atomicOr(&mask[a >> 5], 1u << (a & 31));
  }
  if (tid < 128) {
    float s = gamma[tid] * rsqrtf(var[tid] + 1e-3f);
    scale[tid] = s;
    shift[tid] = (b[tid] - mean[tid]) * s + beta[tid];
  }
  __syncthreads();
  for (int p = tid; p < NBPOS; p += 256) {
    if (!((mask[p >> 5] >> (p & 31)) & 1u)) {
      int q = atomicAdd(&cnt, 1);
      inact[q] = p;   // order nondeterministic; disjoint coverage is what matters
    }
  }
}

// ONE main kernel, 2048 wgs, 1:1 interleave by blockIdx parity so each CU holds
// a mix of MFMA work and HBM-streaming work for the whole kernel.
//   odd idx  -> copy HALF-block (8 rows x 16 cols x 128ch = 64 KB) of inactive
//               block inact[(idx>>1)>>1], row-half (idx>>1)&1. 8 independent
//               16B loads in flight per thread (x2 batches) for HBM MLP.
//   even idx -> conv sub-tile j=idx>>1: M=128 (8 rows x 16 cols) of active
//               block active[j>>1], rows (j&1)*8..+8. K=1152 implicit GEMM.
// Conv: A patch 10x18px x 64ch bf16 LDS (XOR-swizzled, 2 channel halves);
// B ldsB ping-pong write-one-ahead, ONE barrier/K-step. Wave tile 4Mfx4Nf
// (2x2 wave grid): 8 LDS frag-reads per step per wave. 39.4 KB LDS, 4 wg/CU.
__global__ __launch_bounds__(256, 4) void main_kernel(
    const float* __restrict__ x, const __bf16* __restrict__ wprep,
    const float* __restrict__ scale, const float* __restrict__ shift,
    const int* __restrict__ active, const int* __restrict__ inact,
    float* __restrict__ y) {
  __shared__ unsigned char ldsA[180 * 128];   // 10*18 px x 64ch bf16 = 23040 B
  __shared__ unsigned char ldsB[2][8192];     // ping-pong 32k x 128cout bf16

  const int idx = blockIdx.x;
  const int tid = threadIdx.x;

  if (idx & 1) {
    // ---- copy path: half of an inactive block ----
    const int k = idx >> 1;                   // 0..1023
    const int cid = inact[k >> 1];
    const int ch = k & 1;                     // row half
    const int cn = cid >> 8, cy = (cid >> 4) & 15, cx = cid & 15;
    const size_t base4 = ((((size_t)cn * H_ + cy * 16 + ch * 8) * W_ + cx * 16) * C_) >> 2;
    const f32x4* __restrict__ xs = (const f32x4*)x;
    f32x4* __restrict__ ys = (f32x4*)y;
#pragma unroll
    for (int b = 0; b < 2; ++b) {
      f32x4 v[8];
#pragma unroll
      for (int q = 0; q < 8; ++q) {
        int lin = (b * 8 + q) * 256 + tid;    // 16 rows' worth: 8 rows x 512 f32x4
        size_t i4 = base4 + (size_t)(lin >> 9) * (W_ * C_ / 4) + (lin & 511);
        v[q] = xs[i4];
      }
#pragma unroll
      for (int q = 0; q < 8; ++q) {
        int lin = (b * 8 + q) * 256 + tid;
        size_t i4 = base4 + (size_t)(lin >> 9) * (W_ * C_ / 4) + (lin & 511);
        __builtin_nontemporal_store(v[q], &ys[i4]);
      }
    }
    return;
  }

  // ---- conv path ----
  const int j = idx >> 1;                     // 0..1023
  const int lane = tid & 63;
  const int wid = tid >> 6;
  const int wr = wid >> 1, wc = wid & 1;      // 2x2 wave grid
  const int aid = active[j >> 1];
  const int mh = j & 1;                       // spatial half: rows 0-7 or 8-15
  const int bn = aid >> 8, by = (aid >> 4) & 15, bx = aid & 15;
  const int h0 = by * 16, w0 = bx * 16;
  const int hm = h0 + mh * 8;
  const float* xb = x + (size_t)bn * (H_ * W_ * C_);

  f32x4 acc[4][4];
  f32x4 zero = {0.f, 0.f, 0.f, 0.f};
#pragma unroll
  for (int i = 0; i < 4; ++i)
#pragma unroll
    for (int jj = 0; jj < 4; ++jj) acc[i][jj] = zero;

  const uint4* wp4 = (const uint4*)wprep;
  uint4 t0, t1;
  auto load_t = [&](int u) {                  // weight tile for flat K-step u
    int ks = u % 18, h = u / 18;
    int tile = ((ks >> 1) << 2) + (h << 1) + (ks & 1);
    t0 = wp4[tile * 512 + tid];
    t1 = wp4[tile * 512 + 256 + tid];
  };
  auto stage = [&](int half) {                // 10x18 px x 64ch -> bf16 LDS, XOR-swizzled
    for (int u = tid; u < 180 * 8; u += 256) {
      int s = u >> 3, c8 = u & 7;             // s = pr*18 + col
      int pr = s / 18, col = s - pr * 18;
      int hs = hm + pr, wsp = w0 + col;
      float4 f0 = make_float4(0.f, 0.f, 0.f, 0.f), f1 = f0;
      if (hs < H_ && wsp < W_) {
        const float* p = xb + (size_t)(hs * W_ + wsp) * C_ + half * 64 + c8 * 8;
        f0 = *(const float4*)p;
        f1 = *(const float4*)(p + 4);
      }
      bf16x8 v;
      v[0] = (__bf16)f0.x; v[1] = (__bf16)f0.y; v[2] = (__bf16)f0.z; v[3] = (__bf16)f0.w;
      v[4] = (__bf16)f1.x; v[5] = (__bf16)f1.y; v[6] = (__bf16)f1.z; v[7] = (__bf16)f1.w;
      int lin = s * 128 + c8 * 16;
      *(bf16x8*)(&ldsA[lin ^ ((s & 7) << 4)]) = v;
    }
  };

  // prologue
  load_t(0);
  stage(0);
  ((uint4*)ldsB[0])[tid] = t0;
  ((uint4*)ldsB[0])[256 + tid] = t1;
  load_t(1);
  __syncthreads();

  const int koff = (lane >> 4) * 16;          // 16B k-chunk within 32 channels
  const int colb = (lane & 15) * 16;
  const int krow = (lane >> 4) * 2048;

  for (int u = 0; u < 36; ++u) {
    int cur = u & 1;
    if (u < 35) {
      ((uint4*)ldsB[cur ^ 1])[tid] = t0;      // tile u+1
      ((uint4*)ldsB[cur ^ 1])[256 + tid] = t1;
      if (u < 34) load_t(u + 2);
    }
    int ks = u % 18;
    int tap = ks >> 1, kch = ks & 1;
    int dyv = tap / 3, dxv = tap - dyv * 3;

    bf16x8 a[4];
#pragma unroll
    for (int mi = 0; mi < 4; ++mi) {
      int srow = (wr * 4 + mi + dyv) * 18 + dxv + (lane & 15);
      int lin = srow * 128 + kch * 64 + koff;
      a[mi] = *(const bf16x8*)(&ldsA[lin ^ ((srow & 7) << 4)]);
    }
    bf16x8 bfr[4];
#pragma unroll
    for (int nb = 0; nb < 4; ++nb)
      bfr[nb] = *(const bf16x8*)(&ldsB[cur][krow + (wc * 4 + nb) * 256 + colb]);
#pragma unroll
    for (int mi = 0; mi < 4; ++mi)
#pragma unroll
      for (int nb = 0; nb < 4; ++nb)
        acc[mi][nb] = __builtin_amdgcn_mfma_f32_16x16x32_bf16(a[mi], bfr[nb], acc[mi][nb], 0, 0, 0);

    __syncthreads();                          // ldsB[cur] reads done; u+1 writes visible
    if (u == 17) {                            // re-stage ldsA with channel half 1
      stage(1);
      __syncthreads();
    }
  }

  // epilogue: BN + ReLU + scatter. D frag: col=lane&15, row=(lane>>4)*4+reg
  const int colc = lane & 15;
  float sc[4], sh[4];
#pragma unroll
  for (int nb = 0; nb < 4; ++nb) {
    sc[nb] = scale[(wc * 4 + nb) * 16 + colc];
    sh[nb] = shift[(wc * 4 + nb) * 16 + colc];
  }
  float* yb = y + (((size_t)bn * H_ + hm) * W_ + w0) * C_;
#pragma unroll
  for (int mi = 0; mi < 4; ++mi) {
    int oy = wr * 4 + mi;                     // row within this wg's 8-row half
#pragma unroll
    for (int r = 0; r < 4; ++r) {
      int ox = (lane >> 4) * 4 + r;
      float* yr = yb + ((size_t)oy * W_ + ox) * C_;
#pragma unroll
      for (int nb = 0; nb < 4; ++nb) {
        float v = acc[mi][nb][r] * sc[nb] + sh[nb];
        __builtin_nontemporal_store(fmaxf(v, 0.f), &yr[(wc * 4 + nb) * 16 + colc]);
      }
    }
  }
}

extern "C" void kernel_launch(void* const* d_in, const int* in_sizes, int n_in,
                              void* d_out, int out_size, void* d_ws, size_t ws_size,
                              hipStream_t stream) {
  const float* x     = (const float*)d_in[0];
  const float* w     = (const float*)d_in[1];
  const float* b     = (const float*)d_in[2];
  const float* gamma = (const float*)d_in[3];
  const float* beta  = (const float*)d_in[4];
  const float* mean  = (const float*)d_in[5];
  const float* var   = (const float*)d_in[6];
  const int*   act   = (const int*)d_in[7];
  float* y = (float*)d_out;
  char* ws = (char*)d_ws;
  __bf16* wprep = (__bf16*)ws;
  float* scale = (float*)(ws + SCALE_OFF);
  float* shift = (float*)(ws + SHIFT_OFF);
  int* inact = (int*)(ws + INACT_OFF);

  prep_kernel<<<dim3(577), dim3(256), 0, stream>>>(w, b, gamma, beta, mean, var, act,
                                                   wprep, scale, shift, inact);
  main_kernel<<<dim3(2048), dim3(256), 0, stream>>>(x, wprep, scale, shift, act, inact, y);
}

// Round 11
// 75.653 us; speedup vs baseline: 1.2022x; 1.0761x over previous
//
#include <hip/hip_runtime.h>
#include <hip/hip_bf16.h>

#define H_ 256
#define W_ 256
#define C_ 128
#define NBPOS 1024   // N * 16 * 16 block positions
#define NACT 512

typedef __bf16 bf16x8 __attribute__((ext_vector_type(8)));
typedef float f32x4 __attribute__((ext_vector_type(4)));

// workspace layout (bytes)
#define SCALE_OFF 294912
#define SHIFT_OFF 295424
#define INACT_OFF 295936

// Blocks 0..575: weight repack fp32 HWIO -> bf16 [tap][cin8][cout][8].
// Block 576: BN fold + inactive-block list (bitmap + compaction).
__global__ void prep_kernel(const float* __restrict__ w, const float* __restrict__ b,
                            const float* __restrict__ gamma, const float* __restrict__ beta,
                            const float* __restrict__ mean, const float* __restrict__ var,
                            const int* __restrict__ active,
                            __bf16* __restrict__ wprep, float* __restrict__ scale,
                            float* __restrict__ shift, int* __restrict__ inact) {
  int blk = blockIdx.x, tid = threadIdx.x;
  if (blk < 576) {
    int o = blk * 256 + tid;
    int j = o & 7, cout = (o >> 3) & 127, k8 = (o >> 10) & 15, tap = o >> 14;
    wprep[o] = (__bf16)w[((size_t)tap * 128 + k8 * 8 + j) * 128 + cout];
    return;
  }
  __shared__ unsigned mask[32];
  __shared__ int cnt;
  if (tid < 32) mask[tid] = 0u;
  if (tid == 0) cnt = 0;
  __syncthreads();
  for (int i = tid; i < NACT; i += 256) {
    int a = active[i];
    atomicOr(&mask[a >> 5], 1u << (a & 31));
  }
  if (tid < 128) {
    float s = gamma[tid] * rsqrtf(var[tid] + 1e-3f);
    scale[tid] = s;
    shift[tid] = (b[tid] - mean[tid]) * s + beta[tid];
  }
  __syncthreads();
  for (int p = tid; p < NBPOS; p += 256) {
    if (!((mask[p >> 5] >> (p & 31)) & 1u)) {
      int q = atomicAdd(&cnt, 1);
      inact[q] = p;   // order nondeterministic; disjoint coverage is what matters
    }
  }
}

// ONE main kernel, 1536 wgs interleaved 2 conv : 1 copy (R8 structure, best
// measured) with ONE schedule change: the K-loop barrier no longer drains
// vmcnt. Raw s_barrier + lgkmcnt(0) only -> the u+2 weight prefetch (L2
// loads) stays in flight across barriers (AITER / T4 counted-vmcnt pattern).
//   idx%3==2 -> copy wg: stream inactive block inact[idx/3] x->y.
//   else     -> conv wg j=(idx/3)*2+(idx%3): M=128 half-block of active[j>>1].
// Conv: A patch 10x18px x 64ch bf16 LDS (XOR-swizzled); B ldsB ping-pong
// write-one-ahead. 39.4 KB LDS, 4 wg/CU.
__global__ __launch_bounds__(256, 4) void main_kernel(
    const float* __restrict__ x, const __bf16* __restrict__ wprep,
    const float* __restrict__ scale, const float* __restrict__ shift,
    const int* __restrict__ active, const int* __restrict__ inact,
    float* __restrict__ y) {
  __shared__ unsigned char ldsA[180 * 128];   // 10*18 px x 64ch bf16 = 23040 B
  __shared__ unsigned char ldsB[2][8192];     // ping-pong 32k x 128cout bf16

  const int idx = blockIdx.x;
  const int tid = threadIdx.x;

  if (idx % 3 == 2) {
    // ---- copy path: whole inactive block, no barriers, NT stores ----
    const int cid = inact[idx / 3];
    const int cn = cid >> 8, cy = (cid >> 4) & 15, cx = cid & 15;
    const size_t base4 = ((((size_t)cn * H_ + cy * 16) * W_ + cx * 16) * C_) >> 2;
    const f32x4* __restrict__ xs = (const f32x4*)x;
    f32x4* __restrict__ ys = (f32x4*)y;
#pragma unroll 4
    for (int i = 0; i < 32; ++i) {
      int lin = (i << 8) + tid;
      int row = lin >> 9, rem = lin & 511;
      size_t idx4 = base4 + (size_t)row * (W_ * C_ / 4) + rem;
      f32x4 v = xs[idx4];
      __builtin_nontemporal_store(v, &ys[idx4]);
    }
    return;
  }

  // ---- conv path ----
  const int j = (idx / 3) * 2 + (idx % 3);    // 0..1023
  const int lane = tid & 63;
  const int wid = tid >> 6;
  const int aid = active[j >> 1];
  const int mh = j & 1;                       // spatial half: rows 0-7 or 8-15
  const int bn = aid >> 8, by = (aid >> 4) & 15, bx = aid & 15;
  const int h0 = by * 16, w0 = bx * 16;
  const int hm = h0 + mh * 8;
  const float* xb = x + (size_t)bn * (H_ * W_ * C_);

  f32x4 acc[2][8];
  f32x4 zero = {0.f, 0.f, 0.f, 0.f};
#pragma unroll
  for (int i = 0; i < 2; ++i)
#pragma unroll
    for (int jj = 0; jj < 8; ++jj) acc[i][jj] = zero;

  const uint4* wp4 = (const uint4*)wprep;
  uint4 t0, t1;
  auto load_t = [&](int u) {                  // weight tile for flat K-step u
    int ks = u % 18, h = u / 18;
    int tile = ((ks >> 1) << 2) + (h << 1) + (ks & 1);
    t0 = wp4[tile * 512 + tid];
    t1 = wp4[tile * 512 + 256 + tid];
  };
  auto stage = [&](int half) {                // 10x18 px x 64ch -> bf16 LDS, XOR-swizzled
    for (int u = tid; u < 180 * 8; u += 256) {
      int s = u >> 3, c8 = u & 7;             // s = pr*18 + col
      int pr = s / 18, col = s - pr * 18;
      int hs = hm + pr, wsp = w0 + col;
      float4 f0 = make_float4(0.f, 0.f, 0.f, 0.f), f1 = f0;
      if (hs < H_ && wsp < W_) {
        const float* p = xb + (size_t)(hs * W_ + wsp) * C_ + half * 64 + c8 * 8;
        f0 = *(const float4*)p;
        f1 = *(const float4*)(p + 4);
      }
      bf16x8 v;
      v[0] = (__bf16)f0.x; v[1] = (__bf16)f0.y; v[2] = (__bf16)f0.z; v[3] = (__bf16)f0.w;
      v[4] = (__bf16)f1.x; v[5] = (__bf16)f1.y; v[6] = (__bf16)f1.z; v[7] = (__bf16)f1.w;
      int lin = s * 128 + c8 * 16;
      *(bf16x8*)(&ldsA[lin ^ ((s & 7) << 4)]) = v;
    }
  };

  // prologue
  load_t(0);
  stage(0);
  ((uint4*)ldsB[0])[tid] = t0;
  ((uint4*)ldsB[0])[256 + tid] = t1;
  load_t(1);
  __syncthreads();

  const int koff = (lane >> 4) * 16;          // 16B k-chunk within 32 channels
  const int colb = (lane & 15) * 16;
  const int krow = (lane >> 4) * 2048;

  for (int u = 0; u < 36; ++u) {
    int cur = u & 1;
    if (u < 35) {
      ((uint4*)ldsB[cur ^ 1])[tid] = t0;      // tile u+1 (vmcnt dep waits are fine-grained)
      ((uint4*)ldsB[cur ^ 1])[256 + tid] = t1;
      if (u < 34) load_t(u + 2);              // stays in flight ACROSS the barrier
    }
    int ks = u % 18;
    int tap = ks >> 1, kch = ks & 1;
    int dyv = tap / 3, dxv = tap - dyv * 3;

    bf16x8 a[2];
#pragma unroll
    for (int mi = 0; mi < 2; ++mi) {
      int srow = (wid * 2 + mi + dyv) * 18 + dxv + (lane & 15);
      int lin = srow * 128 + kch * 64 + koff;
      a[mi] = *(const bf16x8*)(&ldsA[lin ^ ((srow & 7) << 4)]);
    }
    bf16x8 bfr[8];
#pragma unroll
    for (int nb = 0; nb < 8; ++nb)
      bfr[nb] = *(const bf16x8*)(&ldsB[cur][krow + nb * 256 + colb]);
#pragma unroll
    for (int mi = 0; mi < 2; ++mi)
#pragma unroll
      for (int nb = 0; nb < 8; ++nb)
        acc[mi][nb] = __builtin_amdgcn_mfma_f32_16x16x32_bf16(a[mi], bfr[nb], acc[mi][nb], 0, 0, 0);

    // LDS-only sync: ds_reads/ds_writes retired (lgkmcnt 0), but global
    // prefetch loads (vmcnt) are NOT drained -- no __syncthreads here.
    asm volatile("s_waitcnt lgkmcnt(0)" ::: "memory");
    __builtin_amdgcn_s_barrier();
    __builtin_amdgcn_sched_barrier(0);

    if (u == 17) {                            // re-stage ldsA with channel half 1
      stage(1);
      __syncthreads();
    }
  }

  // epilogue: BN + ReLU + scatter. D frag: col=lane&15, row=(lane>>4)*4+reg
  const int colc = lane & 15;
  float sc[8], sh[8];
#pragma unroll
  for (int nb = 0; nb < 8; ++nb) {
    sc[nb] = scale[nb * 16 + colc];
    sh[nb] = shift[nb * 16 + colc];
  }
  float* yb = y + (((size_t)bn * H_ + hm) * W_ + w0) * C_;
#pragma unroll
  for (int mi = 0; mi < 2; ++mi) {
    int oy = wid * 2 + mi;                    // row within this wg's 8-row half
#pragma unroll
    for (int r = 0; r < 4; ++r) {
      int ox = (lane >> 4) * 4 + r;
      float* yr = yb + ((size_t)oy * W_ + ox) * C_;
#pragma unroll
      for (int nb = 0; nb < 8; ++nb) {
        float v = acc[mi][nb][r] * sc[nb] + sh[nb];
        __builtin_nontemporal_store(fmaxf(v, 0.f), &yr[nb * 16 + colc]);
      }
    }
  }
}

extern "C" void kernel_launch(void* const* d_in, const int* in_sizes, int n_in,
                              void* d_out, int out_size, void* d_ws, size_t ws_size,
                              hipStream_t stream) {
  const float* x     = (const float*)d_in[0];
  const float* w     = (const float*)d_in[1];
  const float* b     = (const float*)d_in[2];
  const float* gamma = (const float*)d_in[3];
  const float* beta  = (const float*)d_in[4];
  const float* mean  = (const float*)d_in[5];
  const float* var   = (const float*)d_in[6];
  const int*   act   = (const int*)d_in[7];
  float* y = (float*)d_out;
  char* ws = (char*)d_ws;
  __bf16* wprep = (__bf16*)ws;
  float* scale = (float*)(ws + SCALE_OFF);
  float* shift = (float*)(ws + SHIFT_OFF);
  int* inact = (int*)(ws + INACT_OFF);

  prep_kernel<<<dim3(577), dim3(256), 0, stream>>>(w, b, gamma, beta, mean, var, act,
                                                   wprep, scale, shift, inact);
  main_kernel<<<dim3(1536), dim3(256), 0, stream>>>(x, wprep, scale, shift, act, inact, y);
}